// Round 7
// baseline (611.959 us; speedup 1.0000x reference)
//
#include <hip/hip_runtime.h>
#include <hip/hip_cooperative_groups.h>
#include <math.h>

namespace cg = cooperative_groups;

// ---------------------------------------------------------------------------
// PrefrontalCortex, batch=1, fp32 — R7: cooperative mega-kernel, 512 blocks.
// R6 failed because 1024 blocks @ 4 blocks/CU co-residency didn't hold and
// the coop launch silently no-op'd (output == memset zeros -> absmax 1.4766
// == stub value). 512 blocks @ __launch_bounds__(256,2) needs only
// VGPR<=256 -> co-residency guaranteed.
// Model (R1-R5): all L2-miss READ traffic caps ~3.1 TB/s chip-wide (L3-hit
// or HBM alike); writes ~7 TB/s. Recoverable time = launch gaps + serial
// spine idling the read pipe. One kernel, 10 phases, idle waves background-
// stream chain-independent weights (W_hh + W_ih x-columns, 16384 row-units).
//
// bg partition (NW=2048 waves): P1 waves1024+ x2 -> [0,2048); P2 waves1024+
// x2 -> [2048,4096); P3 waves4+ x2 -> [4096,8184); P4 waves256+ x2 ->
// [8184,11768); P5 waves4+ x2 -> [11768,15856); P6 waves1024..1551 x1 ->
// [15856,16384). Total 16384 = 8192 GH + 8192 GX.  All bg done before P7.
// ---------------------------------------------------------------------------

#define HIDDEN_DIM 2048
#define MEM_SLOTS 4096
#define MEM_DIM 1024
#define GRID 512
#define NW 2048

typedef float floatx4 __attribute__((ext_vector_type(4)));

static __device__ __forceinline__ float sigmoidf_(float x) {
    return 1.0f / (1.0f + expf(-x));
}

// wave-level dot of one row segment: K4F4 float4 elements (256 or 512).
// Result valid on lane 0.
template<int K4F4>
static __device__ __forceinline__ float rowdot(const float4* __restrict__ Wr,
                                               const float4* __restrict__ v4,
                                               int lane) {
    float a0 = 0.f, a1 = 0.f, a2 = 0.f, a3 = 0.f;
#pragma unroll
    for (int i0 = 0; i0 < K4F4; i0 += 256) {
        int i = i0 + lane;
        floatx4 w0 = *(const floatx4*)(Wr + i);
        floatx4 w1 = *(const floatx4*)(Wr + i + 64);
        floatx4 w2 = *(const floatx4*)(Wr + i + 128);
        floatx4 w3 = *(const floatx4*)(Wr + i + 192);
        floatx4 x0 = *(const floatx4*)(v4 + i);
        floatx4 x1 = *(const floatx4*)(v4 + i + 64);
        floatx4 x2 = *(const floatx4*)(v4 + i + 128);
        floatx4 x3 = *(const floatx4*)(v4 + i + 192);
        a0 = fmaf(w0.x, x0.x, a0); a0 = fmaf(w0.y, x0.y, a0);
        a0 = fmaf(w0.z, x0.z, a0); a0 = fmaf(w0.w, x0.w, a0);
        a1 = fmaf(w1.x, x1.x, a1); a1 = fmaf(w1.y, x1.y, a1);
        a1 = fmaf(w1.z, x1.z, a1); a1 = fmaf(w1.w, x1.w, a1);
        a2 = fmaf(w2.x, x2.x, a2); a2 = fmaf(w2.y, x2.y, a2);
        a2 = fmaf(w2.z, x2.z, a2); a2 = fmaf(w2.w, x2.w, a2);
        a3 = fmaf(w3.x, x3.x, a3); a3 = fmaf(w3.y, x3.y, a3);
        a3 = fmaf(w3.z, x3.z, a3); a3 = fmaf(w3.w, x3.w, a3);
    }
    float acc = (a0 + a1) + (a2 + a3);
#pragma unroll
    for (int off = 32; off > 0; off >>= 1) acc += __shfl_down(acc, off);
    return acc;
}

__launch_bounds__(256, 2)
__global__ void pfc_mega(const float* __restrict__ x, const float* __restrict__ h_prev,
                         const float* __restrict__ c_prev, const float* __restrict__ memory,
                         const float* __restrict__ usage, const float* __restrict__ read_W,
                         const float* __restrict__ read_b, const float* __restrict__ W_ih,
                         const float* __restrict__ b_ih, const float* __restrict__ W_hh,
                         const float* __restrict__ b_hh, const float* __restrict__ head_W,
                         const float* __restrict__ head_b, const float* __restrict__ out_W,
                         const float* __restrict__ out_b, float* __restrict__ d_out,
                         float* __restrict__ ws) {
    cg::grid_group grid = cg::this_grid();
    __shared__ float sm[16];

    const int tid = threadIdx.x;
    const int lane = tid & 63;
    const int wid = tid >> 6;
    const int gw = blockIdx.x * 4 + wid;       // 0..2047

    // ws layout (floats)
    float* rk      = ws;            // 1024
    float* sim     = ws + 1024;     // 4096
    float* rw      = ws + 5120;     // 4096
    float* rv      = ws + 9216;     // 1024
    float* gx      = ws + 10240;    // 8192
    float* gh      = ws + 18432;    // 8192
    float* grv     = ws + 26624;    // 8192
    float* params  = ws + 34816;    // 7169 (pad to 42240)
    float* outh    = ws + 42240;    // 2048
    float* outrv   = ws + 44288;    // 2048
    float* wvv     = ws + 46336;    // 4096
    float* erase   = ws + 50432;    // 1024
    float* addv    = ws + 51456;    // 1024
    float* partial = ws + 52480;    // 64*1024

    // output layout
    float* out       = d_out;
    float* h_new     = d_out + 2048;
    float* c_new     = d_out + 4096;
    float* newmem    = d_out + 6144;
    float* usage_new = d_out + 6144 + (size_t)MEM_SLOTS * MEM_DIM;

    const float4* x4    = (const float4*)x;
    const float4* h4    = (const float4*)h_prev;
    const float4* mem4  = (const float4*)memory;
    const float4* rdw4  = (const float4*)read_W;
    const float4* wih4  = (const float4*)W_ih;
    const float4* whh4  = (const float4*)W_hh;
    const float4* hdw4  = (const float4*)head_W;
    const float4* outw4 = (const float4*)out_W;
    const float4* rk4   = (const float4*)rk;
    const float4* rv4   = (const float4*)rv;
    const float4* hn4   = (const float4*)h_new;

    // background unit: u<8192 -> gh[u] = W_hh[u,:]·h_prev ; else gx row u-8192
    auto do_bg = [&](int u) {
        if (u < 8192) {
            float d = rowdot<512>(whh4 + (size_t)u * 512, h4, lane);
            if (lane == 0) gh[u] = d;
        } else {
            int r = u - 8192;
            float d = rowdot<512>(wih4 + (size_t)r * 768, x4, lane);
            if (lane == 0) gx[r] = d;
        }
    };
    // waves [wavebase, NW) each take 2 consecutive units starting at `start`
    auto bg2 = [&](int start, int wavebase) {
        if (gw >= wavebase) {
            int u = start + (gw - wavebase) * 2;
            do_bg(u);
            do_bg(u + 1);
        }
    };

    // ---- P1: read_key ------------------------------------------------------
    if (gw < 1024) {
        float d = rowdot<512>(rdw4 + (size_t)gw * 512, h4, lane);
        if (lane == 0) rk[gw] = tanhf(d + read_b[gw]);
    }
    bg2(0, 1024);                      // [0,2048)
    grid.sync();

    // ---- P2: sim = memory @ read_key --------------------------------------
    if (gw < 1024) {
#pragma unroll
        for (int p = 0; p < 4; ++p) {
            int r = gw + p * 1024;
            float d = rowdot<256>(mem4 + (size_t)r * 256, rk4, lane);
            if (lane == 0) sim[r] = d;
        }
    }
    bg2(2048, 1024);                   // [2048,4096)
    grid.sync();

    // ---- P3: softmax(sim) -> rw, usage_new --------------------------------
    if (blockIdx.x == 0) {
        float v[16];
        float m = -1e30f;
#pragma unroll
        for (int j = 0; j < 16; ++j) { v[j] = sim[tid + 256 * j]; m = fmaxf(m, v[j]); }
#pragma unroll
        for (int off = 32; off > 0; off >>= 1) m = fmaxf(m, __shfl_down(m, off));
        if (lane == 0) sm[wid] = m;
        __syncthreads();
        if (tid == 0) sm[8] = fmaxf(fmaxf(sm[0], sm[1]), fmaxf(sm[2], sm[3]));
        __syncthreads();
        float mm = sm[8];
        float e[16], s = 0.f;
#pragma unroll
        for (int j = 0; j < 16; ++j) { e[j] = expf(v[j] - mm); s += e[j]; }
#pragma unroll
        for (int off = 32; off > 0; off >>= 1) s += __shfl_down(s, off);
        __syncthreads();
        if (lane == 0) sm[wid] = s;
        __syncthreads();
        if (tid == 0) sm[9] = sm[0] + sm[1] + sm[2] + sm[3];
        __syncthreads();
        float inv = 1.f / sm[9];
#pragma unroll
        for (int j = 0; j < 16; ++j) {
            int idx = tid + 256 * j;
            float r = e[j] * inv;
            rw[idx] = r;
            usage_new[idx] = usage[idx] + r;
        }
    }
    bg2(4096, 4);                      // [4096,8184)
    grid.sync();

    // ---- P4: read_vec partial ---------------------------------------------
    if (blockIdx.x < 64) {
        int chunk = blockIdx.x;
        float4 acc = make_float4(0.f, 0.f, 0.f, 0.f);
        int s0 = chunk * 64;
        for (int s = s0; s < s0 + 64; ++s) {
            float w = rw[s];
            float4 m = mem4[(size_t)s * 256 + tid];
            acc.x = fmaf(w, m.x, acc.x);
            acc.y = fmaf(w, m.y, acc.y);
            acc.z = fmaf(w, m.z, acc.z);
            acc.w = fmaf(w, m.w, acc.w);
        }
        ((float4*)partial)[chunk * 256 + tid] = acc;
    }
    bg2(8184, 256);                    // [8184,11768)
    grid.sync();

    // ---- P5: read_vec reduce ----------------------------------------------
    if (blockIdx.x == 0) {
#pragma unroll
        for (int j = 0; j < 4; ++j) {
            int c = tid + 256 * j;
            float s = 0.f;
            for (int k = 0; k < 64; ++k) s += partial[k * 1024 + c];
            rv[c] = s;
        }
    }
    bg2(11768, 4);                     // [11768,15856)
    grid.sync();

    // ---- P6: grv = W_ih rv-part @ read_vec + last bg ----------------------
    if (gw < 1024) {
#pragma unroll
        for (int p = 0; p < 8; ++p) {
            int u = gw + 1024 * p;
            float d = rowdot<256>(wih4 + (size_t)u * 768 + 512, rv4, lane);
            if (lane == 0) grv[u] = d;
        }
    } else if (gw < 1552) {
        do_bg(15856 + (gw - 1024));    // [15856,16384)
    }
    grid.sync();

    // ---- P7: LSTM elementwise ---------------------------------------------
    if (blockIdx.x == 0) {
#pragma unroll
        for (int j = 0; j < 8; ++j) {
            int t = tid + 256 * j;  // 0..2047
            float gi = gx[t]        + grv[t]        + gh[t]        + b_ih[t]        + b_hh[t];
            float gf = gx[2048 + t] + grv[2048 + t] + gh[2048 + t] + b_ih[2048 + t] + b_hh[2048 + t];
            float gg = gx[4096 + t] + grv[4096 + t] + gh[4096 + t] + b_ih[4096 + t] + b_hh[4096 + t];
            float go = gx[6144 + t] + grv[6144 + t] + gh[6144 + t] + b_ih[6144 + t] + b_hh[6144 + t];
            float c = sigmoidf_(gf) * c_prev[t] + sigmoidf_(gi) * tanhf(gg);
            float h = sigmoidf_(go) * tanhf(c);
            c_new[t] = c;
            h_new[t] = h;
        }
    }
    grid.sync();

    // ---- P8: head (rows 1024..7168) + out_h + out_rv ----------------------
    for (int u = gw; u < 10241; u += NW) {
        if (u < 6145) {
            int r = 1024 + u;
            float d = rowdot<512>(hdw4 + (size_t)r * 512, hn4, lane);
            if (lane == 0) params[r] = d + head_b[r];
        } else if (u < 8193) {
            int o = u - 6145;
            float d = rowdot<512>(outw4 + (size_t)o * 768, hn4, lane);
            if (lane == 0) outh[o] = d;
        } else {
            int o = u - 8193;
            float d = rowdot<256>(outw4 + (size_t)o * 768 + 512, rv4, lane);
            if (lane == 0) outrv[o] = d;
        }
    }
    grid.sync();

    // ---- P9: softmax_w -> wvv, erase, addv --------------------------------
    if (blockIdx.x == 0) {
        const float* logits = params + 3072;
        float v[16];
        float m = -1e30f;
#pragma unroll
        for (int j = 0; j < 16; ++j) { v[j] = logits[tid + 256 * j]; m = fmaxf(m, v[j]); }
#pragma unroll
        for (int off = 32; off > 0; off >>= 1) m = fmaxf(m, __shfl_down(m, off));
        if (lane == 0) sm[wid] = m;
        __syncthreads();
        if (tid == 0) sm[8] = fmaxf(fmaxf(sm[0], sm[1]), fmaxf(sm[2], sm[3]));
        __syncthreads();
        float mm = sm[8];
        float e[16], s = 0.f;
#pragma unroll
        for (int j = 0; j < 16; ++j) { e[j] = expf(v[j] - mm); s += e[j]; }
#pragma unroll
        for (int off = 32; off > 0; off >>= 1) s += __shfl_down(s, off);
        __syncthreads();
        if (lane == 0) sm[wid] = s;
        __syncthreads();
        if (tid == 0) sm[9] = sm[0] + sm[1] + sm[2] + sm[3];
        __syncthreads();
        float gate = sigmoidf_(params[7168]);
        float scale = gate / sm[9];
#pragma unroll
        for (int j = 0; j < 16; ++j) wvv[tid + 256 * j] = e[j] * scale;
#pragma unroll
        for (int j = 0; j < 4; ++j) {
            int idx = tid + 256 * j;
            erase[idx] = sigmoidf_(params[1024 + idx]);
            addv[idx]  = tanhf(params[2048 + idx]);
        }
    }
    grid.sync();

    // ---- P10: memory update (2 slots/wave) + out finalize -----------------
    {
        const float4* e4 = (const float4*)erase;
        const float4* a4 = (const float4*)addv;
        float4* nm4 = (float4*)newmem;
#pragma unroll
        for (int q = 0; q < 2; ++q) {
            int s = gw + q * NW;  // 0..4095
            float w = wvv[s];
            float mask = (usage_new[s] < 0.1f) ? 0.f : 1.f;
#pragma unroll
            for (int j = 0; j < 4; ++j) {
                int ci = lane + 64 * j;          // 0..255 f4 within slot
                size_t idx = (size_t)s * 256 + ci;
                float4 m = mem4[idx];
                float4 e = e4[ci];
                float4 a = a4[ci];
                float4 r;
                r.x = mask * m.x * (1.f - w * e.x) + w * a.x;
                r.y = mask * m.y * (1.f - w * e.y) + w * a.y;
                r.z = mask * m.z * (1.f - w * e.z) + w * a.z;
                r.w = mask * m.w * (1.f - w * e.w) + w * a.w;
                nm4[idx] = r;
            }
        }
        if (gw < 32) {
            int i = gw * 64 + lane;          // 0..2047
            out[i] = outh[i] + outrv[i] + out_b[i];
        }
    }
}

extern "C" void kernel_launch(void* const* d_in, const int* in_sizes, int n_in,
                              void* d_out_, int out_size, void* d_ws, size_t ws_size,
                              hipStream_t stream) {
    const void* x      = d_in[0];
    const void* h_prev = d_in[1];
    const void* c_prev = d_in[2];
    const void* memory = d_in[3];
    const void* usage  = d_in[4];
    const void* read_W = d_in[5];
    const void* read_b = d_in[6];
    const void* W_ih   = d_in[7];
    const void* b_ih   = d_in[8];
    const void* W_hh   = d_in[9];
    const void* b_hh   = d_in[10];
    const void* head_W = d_in[11];
    const void* head_b = d_in[12];
    const void* out_W  = d_in[13];
    const void* out_b  = d_in[14];
    void* d_out = d_out_;
    void* ws = d_ws;

    void* kp[] = {&x, &h_prev, &c_prev, &memory, &usage, &read_W, &read_b,
                  &W_ih, &b_ih, &W_hh, &b_hh, &head_W, &head_b, &out_W, &out_b,
                  &d_out, &ws};
    hipLaunchCooperativeKernel((const void*)pfc_mega, dim3(GRID), dim3(256),
                               kp, 0, stream);
}

// Round 8
// 73.498 us; speedup vs baseline: 8.3262x; 8.3262x over previous
//
#include <hip/hip_runtime.h>
#include <math.h>

// ---------------------------------------------------------------------------
// PrefrontalCortex, batch=1, fp32 — R8: 10 kernels; serial spine overlapped
// with background weight streaming using KERNEL BOUNDARIES as sync.
// R7 lesson: cooperative grid.sync costs ~60us each on 8-XCD gfx950 (9 syncs
// -> 612us). Kernel boundaries give the same device-wide barrier for ~1-2us.
// R7's phase math (gx/gh/grv split, head+out fusion, memupdate+outfin) is
// correctness-verified and reused verbatim.
// bg units: u<8192 -> gh[u]=W_hh[u,:]*h_prev ; u>=8192 -> gx[u-8192]=
// W_ih[u-8192,0:2048]*x. 16384 units = 134 MB spread over K1..K5:
// K1[0,3072) K2[3072,7168) K3[7168,10240) K4[10240,13312) K5[13312,16384).
// ---------------------------------------------------------------------------

#define HIDDEN_DIM 2048
#define MEM_SLOTS 4096
#define MEM_DIM 1024

typedef float floatx4 __attribute__((ext_vector_type(4)));

static __device__ __forceinline__ float sigmoidf_(float x) {
    return 1.0f / (1.0f + expf(-x));
}

// wave-level dot, K4F4 float4 elems (256|512), valid on lane 0.
template<int K4F4>
static __device__ __forceinline__ float rowdot(const float4* __restrict__ Wr,
                                               const float4* __restrict__ v4,
                                               int lane) {
    float a0 = 0.f, a1 = 0.f, a2 = 0.f, a3 = 0.f;
#pragma unroll
    for (int i0 = 0; i0 < K4F4; i0 += 256) {
        int i = i0 + lane;
        floatx4 w0 = *(const floatx4*)(Wr + i);
        floatx4 w1 = *(const floatx4*)(Wr + i + 64);
        floatx4 w2 = *(const floatx4*)(Wr + i + 128);
        floatx4 w3 = *(const floatx4*)(Wr + i + 192);
        floatx4 x0 = *(const floatx4*)(v4 + i);
        floatx4 x1 = *(const floatx4*)(v4 + i + 64);
        floatx4 x2 = *(const floatx4*)(v4 + i + 128);
        floatx4 x3 = *(const floatx4*)(v4 + i + 192);
        a0 = fmaf(w0.x, x0.x, a0); a0 = fmaf(w0.y, x0.y, a0);
        a0 = fmaf(w0.z, x0.z, a0); a0 = fmaf(w0.w, x0.w, a0);
        a1 = fmaf(w1.x, x1.x, a1); a1 = fmaf(w1.y, x1.y, a1);
        a1 = fmaf(w1.z, x1.z, a1); a1 = fmaf(w1.w, x1.w, a1);
        a2 = fmaf(w2.x, x2.x, a2); a2 = fmaf(w2.y, x2.y, a2);
        a2 = fmaf(w2.z, x2.z, a2); a2 = fmaf(w2.w, x2.w, a2);
        a3 = fmaf(w3.x, x3.x, a3); a3 = fmaf(w3.y, x3.y, a3);
        a3 = fmaf(w3.z, x3.z, a3); a3 = fmaf(w3.w, x3.w, a3);
    }
    float acc = (a0 + a1) + (a2 + a3);
#pragma unroll
    for (int off = 32; off > 0; off >>= 1) acc += __shfl_down(acc, off);
    return acc;
}

static __device__ __forceinline__ void do_bg(int u, const float4* whh4,
                                             const float4* wih4, const float4* h4,
                                             const float4* x4, float* gh, float* gx,
                                             int lane) {
    if (u < 8192) {
        float d = rowdot<512>(whh4 + (size_t)u * 512, h4, lane);
        if (lane == 0) gh[u] = d;
    } else {
        int r = u - 8192;
        float d = rowdot<512>(wih4 + (size_t)r * 768, x4, lane);
        if (lane == 0) gx[r] = d;
    }
}

// K1: readkey (blocks 0-255) + bg [0,3072) (blocks 256-1023). grid 1024x256.
__global__ void k1_rk_bg(const float* __restrict__ read_W, const float* __restrict__ read_b,
                         const float* __restrict__ h_prev, const float* __restrict__ W_hh,
                         const float* __restrict__ W_ih, const float* __restrict__ x,
                         float* __restrict__ rk, float* __restrict__ gh, float* __restrict__ gx) {
    int lane = threadIdx.x & 63;
    int gw = blockIdx.x * 4 + (threadIdx.x >> 6);
    const float4* h4 = (const float4*)h_prev;
    if (gw < 1024) {
        float d = rowdot<512>((const float4*)read_W + (size_t)gw * 512, h4, lane);
        if (lane == 0) rk[gw] = tanhf(d + read_b[gw]);
    } else {
        do_bg(gw - 1024, (const float4*)W_hh, (const float4*)W_ih, h4,
              (const float4*)x, gh, gx, lane);
    }
}

// K2: sim (blocks 0-1023) + bg [3072,7168) (blocks 1024-2047). grid 2048x256.
__global__ void k2_sim_bg(const float* __restrict__ memory, const float* __restrict__ rk,
                          const float* __restrict__ h_prev, const float* __restrict__ W_hh,
                          const float* __restrict__ W_ih, const float* __restrict__ x,
                          float* __restrict__ sim, float* __restrict__ gh, float* __restrict__ gx) {
    int lane = threadIdx.x & 63;
    int gw = blockIdx.x * 4 + (threadIdx.x >> 6);
    if (gw < 4096) {
        float d = rowdot<256>((const float4*)memory + (size_t)gw * 256, (const float4*)rk, lane);
        if (lane == 0) sim[gw] = d;
    } else {
        do_bg(3072 + (gw - 4096), (const float4*)W_hh, (const float4*)W_ih,
              (const float4*)h_prev, (const float4*)x, gh, gx, lane);
    }
}

// K3: softmax_rw (block 0, 1024 thr) + bg [7168,10240). grid 193x1024.
__global__ void k3_smx_bg(const float* __restrict__ sim, const float* __restrict__ usage,
                          float* __restrict__ rw, float* __restrict__ usage_out,
                          const float* __restrict__ h_prev, const float* __restrict__ W_hh,
                          const float* __restrict__ W_ih, const float* __restrict__ x,
                          float* __restrict__ gh, float* __restrict__ gx) {
    int tid = threadIdx.x;
    int lane = tid & 63, wid = tid >> 6;
    if (blockIdx.x != 0) {
        int u = 7168 + (blockIdx.x - 1) * 16 + wid;
        do_bg(u, (const float4*)W_hh, (const float4*)W_ih, (const float4*)h_prev,
              (const float4*)x, gh, gx, lane);
        return;
    }
    __shared__ float sm[16];
    float v0 = sim[tid], v1 = sim[tid + 1024], v2 = sim[tid + 2048], v3 = sim[tid + 3072];
    float m = fmaxf(fmaxf(v0, v1), fmaxf(v2, v3));
#pragma unroll
    for (int off = 32; off > 0; off >>= 1) m = fmaxf(m, __shfl_down(m, off));
    if (lane == 0) sm[wid] = m;
    __syncthreads();
    if (tid == 0) {
        float mm = sm[0];
        for (int i = 1; i < 16; ++i) mm = fmaxf(mm, sm[i]);
        sm[0] = mm;
    }
    __syncthreads();
    float mm = sm[0];
    float e0 = expf(v0 - mm), e1 = expf(v1 - mm), e2 = expf(v2 - mm), e3 = expf(v3 - mm);
    float s = e0 + e1 + e2 + e3;
#pragma unroll
    for (int off = 32; off > 0; off >>= 1) s += __shfl_down(s, off);
    __syncthreads();
    if (lane == 0) sm[wid] = s;
    __syncthreads();
    if (tid == 0) {
        float ss = 0.f;
        for (int i = 0; i < 16; ++i) ss += sm[i];
        sm[0] = ss;
    }
    __syncthreads();
    float inv = 1.f / sm[0];
    float r0 = e0 * inv, r1 = e1 * inv, r2 = e2 * inv, r3 = e3 * inv;
    rw[tid] = r0; rw[tid + 1024] = r1; rw[tid + 2048] = r2; rw[tid + 3072] = r3;
    usage_out[tid]        = usage[tid]        + r0;
    usage_out[tid + 1024] = usage[tid + 1024] + r1;
    usage_out[tid + 2048] = usage[tid + 2048] + r2;
    usage_out[tid + 3072] = usage[tid + 3072] + r3;
}

// K4: rv-partial (blocks 0-63) + bg [10240,13312) (blocks 64-831). grid 832x256.
__global__ void k4_rvp_bg(const float* __restrict__ memory, const float* __restrict__ rw,
                          float* __restrict__ partial,
                          const float* __restrict__ h_prev, const float* __restrict__ W_hh,
                          const float* __restrict__ W_ih, const float* __restrict__ x,
                          float* __restrict__ gh, float* __restrict__ gx) {
    int t = threadIdx.x;
    int lane = t & 63;
    if (blockIdx.x >= 64) {
        int u = 10240 + (blockIdx.x - 64) * 4 + (t >> 6);
        do_bg(u, (const float4*)W_hh, (const float4*)W_ih, (const float4*)h_prev,
              (const float4*)x, gh, gx, lane);
        return;
    }
    int chunk = blockIdx.x;
    const float4* mem4 = (const float4*)memory;
    float4 acc = make_float4(0.f, 0.f, 0.f, 0.f);
    int s0 = chunk * 64;
    for (int s = s0; s < s0 + 64; ++s) {
        float w = rw[s];
        float4 m = mem4[(size_t)s * 256 + t];
        acc.x = fmaf(w, m.x, acc.x);
        acc.y = fmaf(w, m.y, acc.y);
        acc.z = fmaf(w, m.z, acc.z);
        acc.w = fmaf(w, m.w, acc.w);
    }
    ((float4*)partial)[chunk * 256 + t] = acc;
}

// K5: rv-reduce (block 0, 1024 thr) + bg [13312,16384). grid 193x1024.
__global__ void k5_rvr_bg(const float* __restrict__ partial, float* __restrict__ rv,
                          const float* __restrict__ h_prev, const float* __restrict__ W_hh,
                          const float* __restrict__ W_ih, const float* __restrict__ x,
                          float* __restrict__ gh, float* __restrict__ gx) {
    int tid = threadIdx.x;
    int lane = tid & 63, wid = tid >> 6;
    if (blockIdx.x != 0) {
        int u = 13312 + (blockIdx.x - 1) * 16 + wid;
        do_bg(u, (const float4*)W_hh, (const float4*)W_ih, (const float4*)h_prev,
              (const float4*)x, gh, gx, lane);
        return;
    }
    float s = 0.f;
    for (int k = 0; k < 64; ++k) s += partial[k * 1024 + tid];
    rv[tid] = s;
}

// K6: grv[u] = W_ih[u, 2048:3072] . rv, 8192 rows. grid 2048x256.
__global__ void k6_grv(const float* __restrict__ W_ih, const float* __restrict__ rv,
                       float* __restrict__ grv) {
    int lane = threadIdx.x & 63;
    int gw = blockIdx.x * 4 + (threadIdx.x >> 6);
    float d = rowdot<256>((const float4*)W_ih + (size_t)gw * 768 + 512, (const float4*)rv, lane);
    if (lane == 0) grv[gw] = d;
}

// K7: LSTM elementwise. grid 8x256.
__global__ void k7_lstm(const float* __restrict__ gx, const float* __restrict__ grv,
                        const float* __restrict__ gh, const float* __restrict__ b_ih,
                        const float* __restrict__ b_hh, const float* __restrict__ c_prev,
                        float* __restrict__ c_new, float* __restrict__ h_new) {
    int t = blockIdx.x * 256 + threadIdx.x;
    float gi = gx[t]        + grv[t]        + gh[t]        + b_ih[t]        + b_hh[t];
    float gf = gx[2048 + t] + grv[2048 + t] + gh[2048 + t] + b_ih[2048 + t] + b_hh[2048 + t];
    float gg = gx[4096 + t] + grv[4096 + t] + gh[4096 + t] + b_ih[4096 + t] + b_hh[4096 + t];
    float go = gx[6144 + t] + grv[6144 + t] + gh[6144 + t] + b_ih[6144 + t] + b_hh[6144 + t];
    float c = sigmoidf_(gf) * c_prev[t] + sigmoidf_(gi) * tanhf(gg);
    float h = sigmoidf_(go) * tanhf(c);
    c_new[t] = c;
    h_new[t] = h;
}

// K8: head rows 1024..7168 (u<6145) + out_h (u<8193) + out_rv (u<10241).
// grid 2561x256.
__global__ void k8_head_out(const float* __restrict__ head_W, const float* __restrict__ head_b,
                            const float* __restrict__ out_W, const float* __restrict__ h_new,
                            const float* __restrict__ rv, float* __restrict__ params,
                            float* __restrict__ outh, float* __restrict__ outrv) {
    int lane = threadIdx.x & 63;
    int u = blockIdx.x * 4 + (threadIdx.x >> 6);
    const float4* hn4 = (const float4*)h_new;
    if (u < 6145) {
        int r = 1024 + u;
        float d = rowdot<512>((const float4*)head_W + (size_t)r * 512, hn4, lane);
        if (lane == 0) params[r] = d + head_b[r];
    } else if (u < 8193) {
        int o = u - 6145;
        float d = rowdot<512>((const float4*)out_W + (size_t)o * 768, hn4, lane);
        if (lane == 0) outh[o] = d;
    } else if (u < 10241) {
        int o = u - 8193;
        float d = rowdot<256>((const float4*)out_W + (size_t)o * 768 + 512, (const float4*)rv, lane);
        if (lane == 0) outrv[o] = d;
    }
}

// K9: softmax_w. grid 1x1024.
__global__ void k9_smxw(const float* __restrict__ params, float* __restrict__ wv,
                        float* __restrict__ erase, float* __restrict__ addv) {
    __shared__ float sm[16];
    int tid = threadIdx.x;
    int lane = tid & 63, wid = tid >> 6;
    const float* logits = params + 3072;
    float v0 = logits[tid], v1 = logits[tid + 1024], v2 = logits[tid + 2048], v3 = logits[tid + 3072];
    float m = fmaxf(fmaxf(v0, v1), fmaxf(v2, v3));
#pragma unroll
    for (int off = 32; off > 0; off >>= 1) m = fmaxf(m, __shfl_down(m, off));
    if (lane == 0) sm[wid] = m;
    __syncthreads();
    if (tid == 0) {
        float mm = sm[0];
        for (int i = 1; i < 16; ++i) mm = fmaxf(mm, sm[i]);
        sm[0] = mm;
    }
    __syncthreads();
    float mm = sm[0];
    float e0 = expf(v0 - mm), e1 = expf(v1 - mm), e2 = expf(v2 - mm), e3 = expf(v3 - mm);
    float s = e0 + e1 + e2 + e3;
#pragma unroll
    for (int off = 32; off > 0; off >>= 1) s += __shfl_down(s, off);
    __syncthreads();
    if (lane == 0) sm[wid] = s;
    __syncthreads();
    if (tid == 0) {
        float ss = 0.f;
        for (int i = 0; i < 16; ++i) ss += sm[i];
        sm[0] = ss;
    }
    __syncthreads();
    float gate = sigmoidf_(params[7168]);
    float scale = gate / sm[0];
    wv[tid] = e0 * scale; wv[tid + 1024] = e1 * scale;
    wv[tid + 2048] = e2 * scale; wv[tid + 3072] = e3 * scale;
    erase[tid] = sigmoidf_(params[1024 + tid]);
    addv[tid]  = tanhf(params[2048 + tid]);
}

// K10: memory update (block = slot) + out finalize on blocks 0-7. grid 4096x256.
__global__ void k10_memupd(const float* __restrict__ memory, const float* __restrict__ wv,
                           const float* __restrict__ erase, const float* __restrict__ addv,
                           const float* __restrict__ usage_new, float* __restrict__ newmem,
                           const float* __restrict__ outh, const float* __restrict__ outrv,
                           const float* __restrict__ out_b, float* __restrict__ out) {
    int s = blockIdx.x;
    int t = threadIdx.x;
    float w = wv[s];
    float mask = (usage_new[s] < 0.1f) ? 0.f : 1.f;
    float4 m = ((const float4*)memory)[(size_t)s * 256 + t];
    float4 e = ((const float4*)erase)[t];
    float4 a = ((const float4*)addv)[t];
    float4 r;
    r.x = mask * m.x * (1.f - w * e.x) + w * a.x;
    r.y = mask * m.y * (1.f - w * e.y) + w * a.y;
    r.z = mask * m.z * (1.f - w * e.z) + w * a.z;
    r.w = mask * m.w * (1.f - w * e.w) + w * a.w;
    ((float4*)newmem)[(size_t)s * 256 + t] = r;
    if (s < 8) {
        int i = s * 256 + t;
        out[i] = outh[i] + outrv[i] + out_b[i];
    }
}

extern "C" void kernel_launch(void* const* d_in, const int* in_sizes, int n_in,
                              void* d_out_, int out_size, void* d_ws, size_t ws_size,
                              hipStream_t stream) {
    const float* x      = (const float*)d_in[0];
    const float* h_prev = (const float*)d_in[1];
    const float* c_prev = (const float*)d_in[2];
    const float* memory = (const float*)d_in[3];
    const float* usage  = (const float*)d_in[4];
    const float* read_W = (const float*)d_in[5];
    const float* read_b = (const float*)d_in[6];
    const float* W_ih   = (const float*)d_in[7];
    const float* b_ih   = (const float*)d_in[8];
    const float* W_hh   = (const float*)d_in[9];
    const float* b_hh   = (const float*)d_in[10];
    const float* head_W = (const float*)d_in[11];
    const float* head_b = (const float*)d_in[12];
    const float* out_W  = (const float*)d_in[13];
    const float* out_b  = (const float*)d_in[14];

    float* d_out = (float*)d_out_;
    float* ws = (float*)d_ws;

    // workspace layout (floats)
    float* rk      = ws;            // 1024
    float* sim     = ws + 1024;     // 4096
    float* rw      = ws + 5120;     // 4096
    float* rv      = ws + 9216;     // 1024
    float* gx      = ws + 10240;    // 8192
    float* gh      = ws + 18432;    // 8192
    float* grv     = ws + 26624;    // 8192
    float* params  = ws + 34816;    // 7169 (pad to 42240)
    float* outh    = ws + 42240;    // 2048
    float* outrv   = ws + 44288;    // 2048
    float* wvv     = ws + 46336;    // 4096
    float* erase   = ws + 50432;    // 1024
    float* addv    = ws + 51456;    // 1024
    float* partial = ws + 52480;    // 64*1024

    // output layout: out | h_new | c_new | new_memory | usage_new
    float* out       = d_out;
    float* h_new     = d_out + 2048;
    float* c_new     = d_out + 4096;
    float* newmem    = d_out + 6144;
    float* usage_new = d_out + 6144 + (size_t)MEM_SLOTS * MEM_DIM;

    k1_rk_bg<<<1024, 256, 0, stream>>>(read_W, read_b, h_prev, W_hh, W_ih, x, rk, gh, gx);
    k2_sim_bg<<<2048, 256, 0, stream>>>(memory, rk, h_prev, W_hh, W_ih, x, sim, gh, gx);
    k3_smx_bg<<<193, 1024, 0, stream>>>(sim, usage, rw, usage_new, h_prev, W_hh, W_ih, x, gh, gx);
    k4_rvp_bg<<<832, 256, 0, stream>>>(memory, rw, partial, h_prev, W_hh, W_ih, x, gh, gx);
    k5_rvr_bg<<<193, 1024, 0, stream>>>(partial, rv, h_prev, W_hh, W_ih, x, gh, gx);
    k6_grv<<<2048, 256, 0, stream>>>(W_ih, rv, grv);
    k7_lstm<<<8, 256, 0, stream>>>(gx, grv, gh, b_ih, b_hh, c_prev, c_new, h_new);
    k8_head_out<<<2561, 256, 0, stream>>>(head_W, head_b, out_W, h_new, rv, params, outh, outrv);
    k9_smxw<<<1, 1024, 0, stream>>>(params, wvv, erase, addv);
    k10_memupd<<<4096, 256, 0, stream>>>(memory, wvv, erase, addv, usage_new, newmem,
                                         outh, outrv, out_b, out);
}